// Round 7
// baseline (128.170 us; speedup 1.0000x reference)
//
#include <hip/hip_runtime.h>
#include <stdint.h>

typedef unsigned short u16;
typedef __attribute__((ext_vector_type(8))) short short8;
typedef __attribute__((ext_vector_type(4))) float f32x4;

#define S_LEN 2048
#define HID   1024
#define QKV_LD 3072
#define M_ROWS 8192   // B*S

__device__ __forceinline__ u16 f2bf(float f) {
  unsigned u = __float_as_uint(f);
  unsigned r = (u + 0x7fffu + ((u >> 16) & 1u)) >> 16;
  return (u16)r;
}

__device__ __forceinline__ void gload16(const u16* g, u16* l) {
  __builtin_amdgcn_global_load_lds(
      (const __attribute__((address_space(1))) unsigned int*)(g),
      (__attribute__((address_space(3))) unsigned int*)(l),
      16, 0, 0);
}

__device__ __forceinline__ void wgbar() {
  asm volatile("" ::: "memory");
  __builtin_amdgcn_s_barrier();
  asm volatile("" ::: "memory");
}

// -------- fused prep: cvt x->bf16, pack biases, transpose 4 weights --------
__global__ __launch_bounds__(256) void prep(
    const float* __restrict__ x, u16* __restrict__ xb,
    const float* __restrict__ bq, const float* __restrict__ bk,
    const float* __restrict__ bv, float* __restrict__ bqkv,
    const float* __restrict__ Wq, const float* __restrict__ Wk,
    const float* __restrict__ Wv, const float* __restrict__ Wo,
    u16* __restrict__ wqkvt, u16* __restrict__ wot) {
  __shared__ float tile[32][33];
  const int bid = blockIdx.x;
  if (bid < 4096) {                      // x: f32 -> bf16, 8 elem/thread
    int i = (bid * 256 + threadIdx.x) * 8;
    float4 a = *(const float4*)(x + i);
    float4 b = *(const float4*)(x + i + 4);
    u16 t[8];
    t[0] = f2bf(a.x); t[1] = f2bf(a.y); t[2] = f2bf(a.z); t[3] = f2bf(a.w);
    t[4] = f2bf(b.x); t[5] = f2bf(b.y); t[6] = f2bf(b.z); t[7] = f2bf(b.w);
    *(short8*)(xb + i) = *(short8*)t;
    return;
  }
  if (bid == 4096) {                     // bias pack
    for (int i = threadIdx.x; i < 3072; i += 256)
      bqkv[i] = (i < 1024) ? bq[i] : (i < 2048) ? bk[i - 1024] : bv[i - 2048];
    return;
  }
  const int wid = bid - 4097;            // weight transpose: f32[K][N]->bf16[N][K]
  const int z = wid >> 10, rem = wid & 1023;
  const float* in = (z == 0) ? Wq : (z == 1) ? Wk : (z == 2) ? Wv : Wo;
  u16* out = (z < 3) ? (wqkvt + (size_t)z * 1024 * 1024) : wot;
  int tx = threadIdx.x & 31, ty = threadIdx.x >> 5;
  int n0 = (rem & 31) * 32, k0 = (rem >> 5) * 32;
#pragma unroll
  for (int i = 0; i < 32; i += 8)
    tile[ty + i][tx] = in[(size_t)(k0 + ty + i) * 1024 + n0 + tx];
  __syncthreads();
#pragma unroll
  for (int i = 0; i < 32; i += 8)
    out[(size_t)(n0 + ty + i) * 1024 + k0 + tx] = f2bf(tile[tx][ty + i]);
}

// ---------------- GEMM1: high-reuse ring-3 counted-vmcnt pipeline --------
// (round-5 geometry, VGPR cap fixed via amdgpu_waves_per_eu(2,2))
// C[8192,3072] = A[8192,1024] * Bt[3072,1024]^T + bias, bf16 out.
// BM=256 x BN=384, BK=32, 8 waves (2M x 4N), per-wave 128x96 (8x6 frags,
// acc=192 VGPR; 48 MFMA & 14 KB frag reads per K-tile -> 55 FLOP/LDS-B).
// Ring-3 LDS slabs of 40 KiB (120 KiB, 1 block/CU); grid 32x8=256 blocks =
// exactly one tail-free CU round.  Prefetch distance 2 K-tiles; ONE
// vmcnt(5) + ONE barrier per K-tile (ring-3 => stage target holds t-1,
// fully read before the end-of-(t-1) barrier -> no aliasing).
// Paired-row LDS layout for BK=32: logical (r,c8) at line (r>>1), slot
// ((r&1)*4+c8)^((r>>1)&7) -> 2 lanes/bank on all reads (free).
__global__ __launch_bounds__(512, 2)
__attribute__((amdgpu_waves_per_eu(2, 2)))
void gemm_k1(
    const u16* __restrict__ A, const u16* __restrict__ Bt,
    const float* __restrict__ bias, u16* __restrict__ C) {
  constexpr int K = 1024, NT = 32, N = 3072;
  constexpr int SLOT = 20480;           // u16 per ring slot (40 KiB)
  constexpr int BOFF = 8192;            // B region offset within slot
  __shared__ __align__(16) u16 smem[3 * SLOT];   // 120 KiB

  const int tid = threadIdx.x;
  const int wave = tid >> 6, lane = tid & 63;
  const int qlane = lane & 15, kgrp = lane >> 4;
  const int wm = wave >> 2, wn = wave & 3;
  int wg = blockIdx.x;
  wg = (wg & 7) * 32 + (wg >> 3);       // 256 blocks over 8 XCDs, bijective
  const int bm = wg >> 3, bn = wg & 7;  // 32 x 8 tiles

  // ---- staging decode (issue = 512 thr x 16 B = 64 line-pairs) ----
  const int trp = tid >> 3, tp = tid & 7;
  uint32_t aoff[2], boff[3];
  int ldsA[2], ldsB[3];
#pragma unroll
  for (int i = 0; i < 2; ++i) {
    int rp = i * 64 + trp, l = tp ^ (rp & 7);
    int r = rp * 2 + (l >> 2), c8 = l & 3;
    aoff[i] = (uint32_t)((bm * 256 + r) * K + c8 * 8);
    ldsA[i] = i * 4096 + tid * 8;
  }
#pragma unroll
  for (int i = 0; i < 3; ++i) {
    int rp = i * 64 + trp, l = tp ^ (rp & 7);
    int r = rp * 2 + (l >> 2), c8 = l & 3;
    boff[i] = (uint32_t)((bn * 384 + r) * K + c8 * 8);
    ldsB[i] = BOFF + i * 4096 + tid * 8;
  }

  // ---- per-thread fragment LDS addresses (u16 units) ----
  int aaddr[8], baddr[6];
#pragma unroll
  for (int mf = 0; mf < 8; ++mf) {
    int r = wm * 128 + mf * 16 + qlane;
    aaddr[mf] = (r >> 1) * 64 + ((((r & 1) << 2) + kgrp) ^ ((r >> 1) & 7)) * 8;
  }
#pragma unroll
  for (int nf = 0; nf < 6; ++nf) {
    int r = wn * 96 + nf * 16 + qlane;
    baddr[nf] = BOFF + (r >> 1) * 64 + ((((r & 1) << 2) + kgrp) ^ ((r >> 1) & 7)) * 8;
  }

  auto stg = [&](int t) {
    u16* base = smem + (t % 3) * SLOT;
#pragma unroll
    for (int i = 0; i < 2; ++i)
      gload16(A + aoff[i] + t * 32, base + ldsA[i]);
#pragma unroll
    for (int i = 0; i < 3; ++i)
      gload16(Bt + boff[i] + t * 32, base + ldsB[i]);
  };

  f32x4 acc[8][6] = {};

  // prologue: tiles 0 and 1 (5 issues each)
  stg(0);
  stg(1);
  asm volatile("s_waitcnt vmcnt(5)" ::: "memory");   // tile 0 landed
  wgbar();

  for (int t = 0; t < NT; ++t) {
    const u16* bp = smem + (t % 3) * SLOT;
    short8 af[8];
#pragma unroll
    for (int mf = 0; mf < 8; ++mf)
      af[mf] = *(const short8*)&bp[aaddr[mf]];
    if (t + 2 < NT) stg(t + 2);
#pragma unroll
    for (int np = 0; np < 3; ++np) {
      short8 bf0 = *(const short8*)&bp[baddr[np * 2]];
      short8 bf1 = *(const short8*)&bp[baddr[np * 2 + 1]];
      __builtin_amdgcn_s_setprio(1);
#pragma unroll
      for (int mf = 0; mf < 8; ++mf) {
        acc[mf][np * 2] = __builtin_amdgcn_mfma_f32_16x16x32_bf16(
            af[mf], bf0, acc[mf][np * 2], 0, 0, 0);
        acc[mf][np * 2 + 1] = __builtin_amdgcn_mfma_f32_16x16x32_bf16(
            af[mf], bf1, acc[mf][np * 2 + 1], 0, 0, 0);
      }
      __builtin_amdgcn_s_setprio(0);
    }
    if (t + 2 < NT)      asm volatile("s_waitcnt vmcnt(5)" ::: "memory");
    else if (t + 1 < NT) asm volatile("s_waitcnt vmcnt(0)" ::: "memory");
    if (t + 1 < NT) wgbar();
  }

  // epilogue
#pragma unroll
  for (int nf = 0; nf < 6; ++nf) {
    int col = bn * 384 + wn * 96 + nf * 16 + qlane;
    float bv = bias[col];
#pragma unroll
    for (int mf = 0; mf < 8; ++mf) {
      int row0 = bm * 256 + wm * 128 + mf * 16 + kgrp * 4;
#pragma unroll
      for (int r = 0; r < 4; ++r)
        C[(size_t)(row0 + r) * N + col] = f2bf(acc[mf][nf][r] + bv);
    }
  }
}

// ---------------- GEMM2: 2-phase ring-2 counted-vmcnt (round-6, proven) ---
__global__ __launch_bounds__(256, 2) void gemm_k2(
    const u16* __restrict__ A, const u16* __restrict__ Bt,
    const float* __restrict__ bias, float* __restrict__ C) {
  constexpr int K = 1024, NT = 16, N = 1024;
  constexpr int AU = 128 * 64;            // 8192 u16
  constexpr int SLAB = 256 * 64;          // 16384 u16 (32 KiB)
  __shared__ __align__(16) u16 smem[2 * SLAB];

  const int tid = threadIdx.x;
  const int wave = tid >> 6, lane = tid & 63;
  const int qlane = lane & 15, kgrp = lane >> 4;
  const int wm = wave >> 1, wn = wave & 1;
  int wg = blockIdx.x;
  wg = (wg & 7) * 64 + (wg >> 3);         // 512 blocks, bijective
  const int bm = wg >> 3, bn = wg & 7;    // 64 x 8

  const int srow = tid >> 3;
  const int sslot = (tid & 7) ^ (srow & 7);
  uint32_t gA[4], gB[4];
#pragma unroll
  for (int u = 0; u < 4; ++u) {
    gA[u] = (uint32_t)((bm * 128 + u * 32 + srow) * K + sslot * 8);
    gB[u] = (uint32_t)((bn * 128 + u * 32 + srow) * K + sslot * 8);
  }
  auto stgA = [&](int t, int u) {
    gload16(A + (size_t)gA[u] + t * 64, &smem[(t & 1) * SLAB + u * 2048 + tid * 8]);
  };
  auto stgB = [&](int t, int u) {
    gload16(Bt + (size_t)gB[u] + t * 64, &smem[(t & 1) * SLAB + AU + u * 2048 + tid * 8]);
  };

  int aaddr[4], baddr[4];
#pragma unroll
  for (int f = 0; f < 4; ++f) {
    aaddr[f] = (wm * 64 + f * 16 + qlane) * 64;
    baddr[f] = AU + (wn * 64 + f * 16 + qlane) * 64;
  }
  const int arow7 = (wm * 64 + qlane) & 7;
  const int brow7 = (wn * 64 + qlane) & 7;

  f32x4 acc[4][4] = {};
  short8 af[4][2], bf[2][2];

#pragma unroll
  for (int u = 0; u < 4; ++u) stgA(0, u);
#pragma unroll
  for (int u = 0; u < 4; ++u) stgB(0, u);
#pragma unroll
  for (int u = 0; u < 4; ++u) stgA(1, u);
  stgB(1, 0); stgB(1, 2);
  asm volatile("s_waitcnt vmcnt(6)" ::: "memory");
  wgbar();

  for (int t = 0; t < NT; ++t) {
    const u16* bp = &smem[(t & 1) * SLAB];

    // ---- P1 ----
#pragma unroll
    for (int mf = 0; mf < 4; ++mf)
#pragma unroll
      for (int kk = 0; kk < 2; ++kk)
        af[mf][kk] = *(const short8*)&bp[aaddr[mf] + (((kk * 4 + kgrp) ^ arow7) * 8)];
#pragma unroll
    for (int nf = 0; nf < 2; ++nf)
#pragma unroll
      for (int kk = 0; kk < 2; ++kk)
        bf[nf][kk] = *(const short8*)&bp[baddr[nf] + (((kk * 4 + kgrp) ^ brow7) * 8)];
    if (t + 1 < NT) { stgB(t + 1, 1); stgB(t + 1, 3); }
    wgbar();
    asm volatile("s_waitcnt lgkmcnt(0)" ::: "memory");
    __builtin_amdgcn_s_setprio(1);
#pragma unroll
    for (int mf = 0; mf < 4; ++mf)
#pragma unroll
      for (int nf = 0; nf < 2; ++nf)
#pragma unroll
        for (int kk = 0; kk < 2; ++kk)
          acc[mf][nf] = __builtin_amdgcn_mfma_f32_16x16x32_bf16(
              af[mf][kk], bf[nf][kk], acc[mf][nf], 0, 0, 0);
    __builtin_amdgcn_s_setprio(0);
    wgbar();

    // ---- P2 ----
#pragma unroll
    for (int nf = 0; nf < 2; ++nf)
#pragma unroll
      for (int kk = 0; kk < 2; ++kk)
        bf[nf][kk] = *(const short8*)&bp[baddr[nf + 2] + (((kk * 4 + kgrp) ^ brow7) * 8)];
    if (t + 2 < NT) {
      stgA(t + 2, 0); stgA(t + 2, 1); stgA(t + 2, 2); stgA(t + 2, 3);
      stgB(t + 2, 0); stgB(t + 2, 2);
    }
    wgbar();
    asm volatile("s_waitcnt lgkmcnt(0)" ::: "memory");
    __builtin_amdgcn_s_setprio(1);
#pragma unroll
    for (int mf = 0; mf < 4; ++mf)
#pragma unroll
      for (int nf = 0; nf < 2; ++nf)
#pragma unroll
        for (int kk = 0; kk < 2; ++kk)
          acc[mf][nf + 2] = __builtin_amdgcn_mfma_f32_16x16x32_bf16(
              af[mf][kk], bf[nf][kk], acc[mf][nf + 2], 0, 0, 0);
    __builtin_amdgcn_s_setprio(0);
    if (t + 2 < NT)      asm volatile("s_waitcnt vmcnt(6)" ::: "memory");
    else if (t + 1 < NT) asm volatile("s_waitcnt vmcnt(0)" ::: "memory");
    if (t + 1 < NT) wgbar();
  }

#pragma unroll
  for (int nf = 0; nf < 4; ++nf) {
    int col = bn * 128 + wn * 64 + nf * 16 + qlane;
    float bv = bias[col];
#pragma unroll
    for (int mf = 0; mf < 4; ++mf) {
      int row0 = bm * 128 + wm * 64 + mf * 16 + kgrp * 4;
#pragma unroll
      for (int r = 0; r < 4; ++r)
        C[(size_t)(row0 + r) * N + col] = acc[mf][nf][r] + bv;
    }
  }
}

// ---------------- banded local attention (unchanged, proven) ----------------
__global__ __launch_bounds__(256, 2) void attn_local(
    const u16* __restrict__ qkv, const int* __restrict__ amask,
    u16* __restrict__ aout) {
  __shared__ __align__(16) u16 Kl[192][72];
  __shared__ __align__(16) u16 Vt[64][200];
  __shared__ __align__(16) u16 Pl[4][32][104];

  const int tid = threadIdx.x, wave = tid >> 6, lane = tid & 63;
  const int qlane = lane & 15, kgrp = lane >> 4;
  const int bz = blockIdx.x;
  const int qt = bz & 15, h = (bz >> 4) & 15, b = bz >> 8;
  const int qs0 = qt * 128;
  const int jt = qs0 - 32;
  const size_t rbase = (size_t)b * S_LEN;

  {
    const int r0 = tid >> 3, c0 = (tid & 7) * 8;
#pragma unroll
    for (int p = 0; p < 6; ++p) {
      int row = p * 32 + r0;
      int j = jt + row;
      u16 kv[8], vv[8];
      if (j >= 0 && j < S_LEN) {
        const u16* kp = qkv + (rbase + j) * QKV_LD + HID + h * 64 + c0;
        *(short8*)kv = *(const short8*)kp;
        *(short8*)vv = *(const short8*)(kp + HID);
      } else {
#pragma unroll
        for (int q = 0; q < 8; ++q) { kv[q] = 0; vv[q] = 0; }
      }
      *(short8*)&Kl[row][c0] = *(short8*)kv;
#pragma unroll
      for (int q = 0; q < 8; ++q) Vt[c0 + q][row] = vv[q];
    }
  }

  short8 qf[2][2];
#pragma unroll
  for (int mf = 0; mf < 2; ++mf)
#pragma unroll
    for (int kk = 0; kk < 2; ++kk)
      qf[mf][kk] = *(const short8*)(qkv +
          (rbase + qs0 + wave * 32 + mf * 16 + qlane) * QKV_LD +
          h * 64 + kk * 32 + kgrp * 8);

  __syncthreads();

  f32x4 sc[2][6] = {};
#pragma unroll
  for (int kk = 0; kk < 2; ++kk) {
    short8 kf[6];
#pragma unroll
    for (int nf = 0; nf < 6; ++nf)
      kf[nf] = *(const short8*)&Kl[wave * 32 + nf * 16 + qlane][kk * 32 + kgrp * 8];
#pragma unroll
    for (int mf = 0; mf < 2; ++mf)
#pragma unroll
      for (int nf = 0; nf < 6; ++nf)
        sc[mf][nf] = __builtin_amdgcn_mfma_f32_16x16x32_bf16(
            qf[mf][kk], kf[nf], sc[mf][nf], 0, 0, 0);
  }

  int jcol[6], mv[6];
#pragma unroll
  for (int nf = 0; nf < 6; ++nf) {
    int j = jt + wave * 32 + nf * 16 + qlane;
    jcol[nf] = j;
    mv[nf] = (j >= 0 && j < S_LEN) ? amask[rbase + j] : 0;
  }

  float inv[2][4];
#pragma unroll
  for (int mf = 0; mf < 2; ++mf) {
    const int irow0 = qs0 + wave * 32 + mf * 16 + kgrp * 4;
    float mx[4] = {-1e30f, -1e30f, -1e30f, -1e30f};
#pragma unroll
    for (int r = 0; r < 4; ++r) {
      int i = irow0 + r;
#pragma unroll
      for (int nf = 0; nf < 6; ++nf) {
        int d = i - jcol[nf];
        if (mv[nf] && d >= -32 && d <= 32) mx[r] = fmaxf(mx[r], sc[mf][nf][r]);
      }
    }
#pragma unroll
    for (int m = 1; m < 16; m <<= 1)
#pragma unroll
      for (int r = 0; r < 4; ++r)
        mx[r] = fmaxf(mx[r], __shfl_xor(mx[r], m));
    float sm[4] = {0.f, 0.f, 0.f, 0.f};
#pragma unroll
    for (int r = 0; r < 4; ++r) {
      int i = irow0 + r;
#pragma unroll
      for (int nf = 0; nf < 6; ++nf) {
        int d = i - jcol[nf];
        bool val = mv[nf] && d >= -32 && d <= 32;
        float p = val ? __expf((sc[mf][nf][r] - mx[r]) * 0.125f) : 0.f;
        sc[mf][nf][r] = p;
        sm[r] += p;
      }
    }
#pragma unroll
    for (int m = 1; m < 16; m <<= 1)
#pragma unroll
      for (int r = 0; r < 4; ++r)
        sm[r] += __shfl_xor(sm[r], m);
#pragma unroll
    for (int r = 0; r < 4; ++r)
      inv[mf][r] = sm[r] > 0.f ? 1.f / sm[r] : 0.f;
#pragma unroll
    for (int nf = 0; nf < 6; ++nf)
#pragma unroll
      for (int r = 0; r < 4; ++r)
        Pl[wave][mf * 16 + kgrp * 4 + r][nf * 16 + qlane] = f2bf(sc[mf][nf][r]);
  }
  __syncthreads();

  f32x4 oc[2][4] = {};
#pragma unroll
  for (int ks = 0; ks < 3; ++ks) {
    short8 pa[2], vb[4];
#pragma unroll
    for (int mf = 0; mf < 2; ++mf)
      pa[mf] = *(const short8*)&Pl[wave][mf * 16 + qlane][ks * 32 + kgrp * 8];
#pragma unroll
    for (int nf = 0; nf < 4; ++nf)
      vb[nf] = *(const short8*)&Vt[nf * 16 + qlane][wave * 32 + ks * 32 + kgrp * 8];
#pragma unroll
    for (int mf = 0; mf < 2; ++mf)
#pragma unroll
      for (int nf = 0; nf < 4; ++nf)
        oc[mf][nf] = __builtin_amdgcn_mfma_f32_16x16x32_bf16(
            pa[mf], vb[nf], oc[mf][nf], 0, 0, 0);
  }

#pragma unroll
  for (int mf = 0; mf < 2; ++mf)
#pragma unroll
    for (int nf = 0; nf < 4; ++nf)
#pragma unroll
      for (int r = 0; r < 4; ++r) {
        size_t row = rbase + qs0 + wave * 32 + mf * 16 + kgrp * 4 + r;
        aout[row * HID + h * 64 + nf * 16 + qlane] =
            f2bf(oc[mf][nf][r] * inv[mf][r]);
      }
}

// ---------------- launch ----------------
extern "C" void kernel_launch(void* const* d_in, const int* in_sizes, int n_in,
                              void* d_out, int out_size, void* d_ws, size_t ws_size,
                              hipStream_t stream) {
  const float* x  = (const float*)d_in[0];
  const int* amask = (const int*)d_in[1];
  const float* Wq = (const float*)d_in[2];
  const float* bq = (const float*)d_in[3];
  const float* Wk = (const float*)d_in[4];
  const float* bk = (const float*)d_in[5];
  const float* Wv = (const float*)d_in[6];
  const float* bv = (const float*)d_in[7];
  const float* Wo = (const float*)d_in[8];
  const float* bo = (const float*)d_in[9];
  float* out = (float*)d_out;

  char* w = (char*)d_ws;
  u16* xb    = (u16*)w;   w += (size_t)M_ROWS * HID * 2;
  u16* wqkvt = (u16*)w;   w += (size_t)3072 * 1024 * 2;
  u16* wot   = (u16*)w;   w += (size_t)1024 * 1024 * 2;
  float* bqkv = (float*)w; w += 3072 * 4 + 256;
  u16* qkv   = (u16*)w;   w += (size_t)M_ROWS * 3072 * 2;
  u16* aout  = (u16*)w;   w += (size_t)M_ROWS * HID * 2;

  prep<<<8193, 256, 0, stream>>>(x, xb, bq, bk, bv, bqkv,
                                 Wq, Wk, Wv, Wo, wqkvt, wot);
  gemm_k1<<<256, 512, 0, stream>>>(xb, wqkvt, bqkv, qkv);
  attn_local<<<1024, 256, 0, stream>>>(qkv, amask, aout);
  gemm_k2<<<512, 256, 0, stream>>>(aout, wot, bo, out);
}

// Round 8
// 119.964 us; speedup vs baseline: 1.0684x; 1.0684x over previous
//
#include <hip/hip_runtime.h>
#include <stdint.h>

typedef unsigned short u16;
typedef __attribute__((ext_vector_type(8))) short short8;
typedef __attribute__((ext_vector_type(4))) float f32x4;
typedef __attribute__((ext_vector_type(16))) float f32x16;

#define S_LEN 2048
#define HID   1024
#define QKV_LD 3072
#define M_ROWS 8192   // B*S

__device__ __forceinline__ u16 f2bf(float f) {
  unsigned u = __float_as_uint(f);
  unsigned r = (u + 0x7fffu + ((u >> 16) & 1u)) >> 16;
  return (u16)r;
}

__device__ __forceinline__ void gload16(const u16* g, u16* l) {
  __builtin_amdgcn_global_load_lds(
      (const __attribute__((address_space(1))) unsigned int*)(g),
      (__attribute__((address_space(3))) unsigned int*)(l),
      16, 0, 0);
}

__device__ __forceinline__ void wgbar() {
  asm volatile("" ::: "memory");
  __builtin_amdgcn_s_barrier();
  asm volatile("" ::: "memory");
}

// -------- fused prep: cvt x->bf16, pack biases, transpose 4 weights --------
__global__ __launch_bounds__(256) void prep(
    const float* __restrict__ x, u16* __restrict__ xb,
    const float* __restrict__ bq, const float* __restrict__ bk,
    const float* __restrict__ bv, float* __restrict__ bqkv,
    const float* __restrict__ Wq, const float* __restrict__ Wk,
    const float* __restrict__ Wv, const float* __restrict__ Wo,
    u16* __restrict__ wqkvt, u16* __restrict__ wot) {
  __shared__ float tile[32][33];
  const int bid = blockIdx.x;
  if (bid < 4096) {                      // x: f32 -> bf16, 8 elem/thread
    int i = (bid * 256 + threadIdx.x) * 8;
    float4 a = *(const float4*)(x + i);
    float4 b = *(const float4*)(x + i + 4);
    u16 t[8];
    t[0] = f2bf(a.x); t[1] = f2bf(a.y); t[2] = f2bf(a.z); t[3] = f2bf(a.w);
    t[4] = f2bf(b.x); t[5] = f2bf(b.y); t[6] = f2bf(b.z); t[7] = f2bf(b.w);
    *(short8*)(xb + i) = *(short8*)t;
    return;
  }
  if (bid == 4096) {                     // bias pack
    for (int i = threadIdx.x; i < 3072; i += 256)
      bqkv[i] = (i < 1024) ? bq[i] : (i < 2048) ? bk[i - 1024] : bv[i - 2048];
    return;
  }
  const int wid = bid - 4097;            // weight transpose: f32[K][N]->bf16[N][K]
  const int z = wid >> 10, rem = wid & 1023;
  const float* in = (z == 0) ? Wq : (z == 1) ? Wk : (z == 2) ? Wv : Wo;
  u16* out = (z < 3) ? (wqkvt + (size_t)z * 1024 * 1024) : wot;
  int tx = threadIdx.x & 31, ty = threadIdx.x >> 5;
  int n0 = (rem & 31) * 32, k0 = (rem >> 5) * 32;
#pragma unroll
  for (int i = 0; i < 32; i += 8)
    tile[ty + i][tx] = in[(size_t)(k0 + ty + i) * 1024 + n0 + tx];
  __syncthreads();
#pragma unroll
  for (int i = 0; i < 32; i += 8)
    out[(size_t)(n0 + ty + i) * 1024 + k0 + tx] = f2bf(tile[tx][ty + i]);
}

// ---------------- GEMM1: 2-phase ring-2 pipeline, 32x32x16 MFMA ----------
// C[8192,3072] = A * Bt^T + bias (bf16 out).  BM=128 x BN=192, BK=64,
// 4 waves (2M x 2N), per-wave 64x96 = 2x3 frags of 32x32 (acc 96 VGPR).
// Same control flow / staging schedule / race-freedom proof as round 6;
// only the MFMA shape changed (24 instead of 48 MFMA per wave-tile,
// 4060 vs 3378 FLOP/cyc pipe efficiency).
// Frag layouts (32x32x16_bf16): A/B lane holds row|col = lane&31,
// k = (lane>>5)*8 + j.  C/D: col = lane&31, row = (reg&3)+8*(reg>>2)
// +4*(lane>>5)  [m74/m101].
// P1 reads: A units 0-3 + B units {0,1,3,4} (nf0,1); stages B{2,5}(t+1).
// P2 reads: B units {2,5} (nf2); stages A(t+2) + B{0,1,3,4}(t+2).
// Gate vmcnt(8) at tile end: 8 newest = t+2's -> t+1 fully landed.
__global__ __launch_bounds__(256, 2) void gemm_k1(
    const u16* __restrict__ A, const u16* __restrict__ Bt,
    const float* __restrict__ bias, u16* __restrict__ C) {
  constexpr int K = 1024, NT = 16, N = 3072;
  constexpr int AU = 128 * 64;            // 8192 u16
  constexpr int SLAB = 320 * 64;          // 20480 u16 (40 KiB)
  __shared__ __align__(16) u16 smem[2 * SLAB];

  const int tid = threadIdx.x;
  const int wave = tid >> 6, lane = tid & 63;
  const int l31 = lane & 31, kh = lane >> 5;   // frag row offset, k-half
  const int wm = wave >> 1, wn = wave & 1;
  int wg = blockIdx.x;
  wg = (wg & 7) * 128 + (wg >> 3);        // 1024 blocks, bijective XCD swizzle
  const int bm = wg >> 4, bn = wg & 15;   // 64 x 16

  // staging: unit = 32 rows x 64 cols = 4 KiB = 256 thr x 16 B
  const int srow = tid >> 3;
  const int sslot = (tid & 7) ^ (srow & 7);
  uint32_t gA[4], gB[6];
#pragma unroll
  for (int u = 0; u < 4; ++u)
    gA[u] = (uint32_t)((bm * 128 + u * 32 + srow) * K + sslot * 8);
#pragma unroll
  for (int u = 0; u < 6; ++u)
    gB[u] = (uint32_t)((bn * 192 + u * 32 + srow) * K + sslot * 8);

  auto stgA = [&](int t, int u) {
    gload16(A + (size_t)gA[u] + t * 64, &smem[(t & 1) * SLAB + u * 2048 + tid * 8]);
  };
  auto stgB = [&](int t, int u) {
    gload16(Bt + (size_t)gB[u] + t * 64, &smem[(t & 1) * SLAB + AU + u * 2048 + tid * 8]);
  };

  // frag base addresses (u16 units); row&7 == lane&7 for all frags
  const int key7 = lane & 7;
  int aaddr[2], baddr[3];
#pragma unroll
  for (int mf = 0; mf < 2; ++mf)
    aaddr[mf] = (wm * 64 + mf * 32 + l31) * 64;
#pragma unroll
  for (int nf = 0; nf < 3; ++nf)
    baddr[nf] = AU + (wn * 96 + nf * 32 + l31) * 64;

  f32x16 acc[2][3] = {};
  short8 af[2][4], bf[2][4];

  // prologue: tile 0 (10 loads) + A(1),B{0,1,3,4}(1) (8 loads)
#pragma unroll
  for (int u = 0; u < 4; ++u) stgA(0, u);
#pragma unroll
  for (int u = 0; u < 6; ++u) stgB(0, u);
#pragma unroll
  for (int u = 0; u < 4; ++u) stgA(1, u);
  stgB(1, 0); stgB(1, 1); stgB(1, 3); stgB(1, 4);
  asm volatile("s_waitcnt vmcnt(8)" ::: "memory");   // tile 0 landed
  wgbar();

  for (int t = 0; t < NT; ++t) {
    const u16* bp = &smem[(t & 1) * SLAB];

    // ---- P1: read A (8) + B nf0,1 (8); stage B{2,5}(t+1) ----
#pragma unroll
    for (int mf = 0; mf < 2; ++mf)
#pragma unroll
      for (int kk = 0; kk < 4; ++kk)
        af[mf][kk] = *(const short8*)&bp[aaddr[mf] + (((kk * 2 + kh) ^ key7) * 8)];
#pragma unroll
    for (int nf = 0; nf < 2; ++nf)
#pragma unroll
      for (int kk = 0; kk < 4; ++kk)
        bf[nf][kk] = *(const short8*)&bp[baddr[nf] + (((kk * 2 + kh) ^ key7) * 8)];
    if (t + 1 < NT) { stgB(t + 1, 2); stgB(t + 1, 5); }
    wgbar();
    asm volatile("s_waitcnt lgkmcnt(0)" ::: "memory");
    __builtin_amdgcn_s_setprio(1);
#pragma unroll
    for (int mf = 0; mf < 2; ++mf)
#pragma unroll
      for (int nf = 0; nf < 2; ++nf)
#pragma unroll
        for (int kk = 0; kk < 4; ++kk)
          acc[mf][nf] = __builtin_amdgcn_mfma_f32_32x32x16_bf16(
              af[mf][kk], bf[nf][kk], acc[mf][nf], 0, 0, 0);
    __builtin_amdgcn_s_setprio(0);
    wgbar();

    // ---- P2: read B nf2 (4); stage A(t+2) + B{0,1,3,4}(t+2) ----
#pragma unroll
    for (int kk = 0; kk < 4; ++kk)
      bf[0][kk] = *(const short8*)&bp[baddr[2] + (((kk * 2 + kh) ^ key7) * 8)];
    if (t + 2 < NT) {
      stgA(t + 2, 0); stgA(t + 2, 1); stgA(t + 2, 2); stgA(t + 2, 3);
      stgB(t + 2, 0); stgB(t + 2, 1); stgB(t + 2, 3); stgB(t + 2, 4);
    }
    wgbar();
    asm volatile("s_waitcnt lgkmcnt(0)" ::: "memory");
    __builtin_amdgcn_s_setprio(1);
#pragma unroll
    for (int mf = 0; mf < 2; ++mf)
#pragma unroll
      for (int kk = 0; kk < 4; ++kk)
        acc[mf][2] = __builtin_amdgcn_mfma_f32_32x32x16_bf16(
            af[mf][kk], bf[0][kk], acc[mf][2], 0, 0, 0);
    __builtin_amdgcn_s_setprio(0);
    if (t + 2 < NT)      asm volatile("s_waitcnt vmcnt(8)" ::: "memory");
    else if (t + 1 < NT) asm volatile("s_waitcnt vmcnt(0)" ::: "memory");
    if (t + 1 < NT) wgbar();
  }

  // epilogue: C/D layout col=lane&31, row=(reg&3)+8*(reg>>2)+4*kh
#pragma unroll
  for (int nf = 0; nf < 3; ++nf) {
    int col = bn * 192 + wn * 96 + nf * 32 + l31;
    float bv = bias[col];
#pragma unroll
    for (int mf = 0; mf < 2; ++mf) {
      int rbase = bm * 128 + wm * 64 + mf * 32 + kh * 4;
#pragma unroll
      for (int reg = 0; reg < 16; ++reg) {
        int row = rbase + (reg & 3) + 8 * (reg >> 2);
        C[(size_t)row * N + col] = f2bf(acc[mf][nf][reg] + bv);
      }
    }
  }
}

// ---------------- GEMM2: 2-phase ring-2 counted-vmcnt (round-6, proven) ---
__global__ __launch_bounds__(256, 2) void gemm_k2(
    const u16* __restrict__ A, const u16* __restrict__ Bt,
    const float* __restrict__ bias, float* __restrict__ C) {
  constexpr int K = 1024, NT = 16, N = 1024;
  constexpr int AU = 128 * 64;            // 8192 u16
  constexpr int SLAB = 256 * 64;          // 16384 u16 (32 KiB)
  __shared__ __align__(16) u16 smem[2 * SLAB];

  const int tid = threadIdx.x;
  const int wave = tid >> 6, lane = tid & 63;
  const int qlane = lane & 15, kgrp = lane >> 4;
  const int wm = wave >> 1, wn = wave & 1;
  int wg = blockIdx.x;
  wg = (wg & 7) * 64 + (wg >> 3);         // 512 blocks, bijective
  const int bm = wg >> 3, bn = wg & 7;    // 64 x 8

  const int srow = tid >> 3;
  const int sslot = (tid & 7) ^ (srow & 7);
  uint32_t gA[4], gB[4];
#pragma unroll
  for (int u = 0; u < 4; ++u) {
    gA[u] = (uint32_t)((bm * 128 + u * 32 + srow) * K + sslot * 8);
    gB[u] = (uint32_t)((bn * 128 + u * 32 + srow) * K + sslot * 8);
  }
  auto stgA = [&](int t, int u) {
    gload16(A + (size_t)gA[u] + t * 64, &smem[(t & 1) * SLAB + u * 2048 + tid * 8]);
  };
  auto stgB = [&](int t, int u) {
    gload16(Bt + (size_t)gB[u] + t * 64, &smem[(t & 1) * SLAB + AU + u * 2048 + tid * 8]);
  };

  int aaddr[4], baddr[4];
#pragma unroll
  for (int f = 0; f < 4; ++f) {
    aaddr[f] = (wm * 64 + f * 16 + qlane) * 64;
    baddr[f] = AU + (wn * 64 + f * 16 + qlane) * 64;
  }
  const int arow7 = (wm * 64 + qlane) & 7;
  const int brow7 = (wn * 64 + qlane) & 7;

  f32x4 acc[4][4] = {};
  short8 af[4][2], bf[2][2];

#pragma unroll
  for (int u = 0; u < 4; ++u) stgA(0, u);
#pragma unroll
  for (int u = 0; u < 4; ++u) stgB(0, u);
#pragma unroll
  for (int u = 0; u < 4; ++u) stgA(1, u);
  stgB(1, 0); stgB(1, 2);
  asm volatile("s_waitcnt vmcnt(6)" ::: "memory");
  wgbar();

  for (int t = 0; t < NT; ++t) {
    const u16* bp = &smem[(t & 1) * SLAB];

    // ---- P1 ----
#pragma unroll
    for (int mf = 0; mf < 4; ++mf)
#pragma unroll
      for (int kk = 0; kk < 2; ++kk)
        af[mf][kk] = *(const short8*)&bp[aaddr[mf] + (((kk * 4 + kgrp) ^ arow7) * 8)];
#pragma unroll
    for (int nf = 0; nf < 2; ++nf)
#pragma unroll
      for (int kk = 0; kk < 2; ++kk)
        bf[nf][kk] = *(const short8*)&bp[baddr[nf] + (((kk * 4 + kgrp) ^ brow7) * 8)];
    if (t + 1 < NT) { stgB(t + 1, 1); stgB(t + 1, 3); }
    wgbar();
    asm volatile("s_waitcnt lgkmcnt(0)" ::: "memory");
    __builtin_amdgcn_s_setprio(1);
#pragma unroll
    for (int mf = 0; mf < 4; ++mf)
#pragma unroll
      for (int nf = 0; nf < 2; ++nf)
#pragma unroll
        for (int kk = 0; kk < 2; ++kk)
          acc[mf][nf] = __builtin_amdgcn_mfma_f32_16x16x32_bf16(
              af[mf][kk], bf[nf][kk], acc[mf][nf], 0, 0, 0);
    __builtin_amdgcn_s_setprio(0);
    wgbar();

    // ---- P2 ----
#pragma unroll
    for (int nf = 0; nf < 2; ++nf)
#pragma unroll
      for (int kk = 0; kk < 2; ++kk)
        bf[nf][kk] = *(const short8*)&bp[baddr[nf + 2] + (((kk * 4 + kgrp) ^ brow7) * 8)];
    if (t + 2 < NT) {
      stgA(t + 2, 0); stgA(t + 2, 1); stgA(t + 2, 2); stgA(t + 2, 3);
      stgB(t + 2, 0); stgB(t + 2, 2);
    }
    wgbar();
    asm volatile("s_waitcnt lgkmcnt(0)" ::: "memory");
    __builtin_amdgcn_s_setprio(1);
#pragma unroll
    for (int mf = 0; mf < 4; ++mf)
#pragma unroll
      for (int nf = 0; nf < 2; ++nf)
#pragma unroll
        for (int kk = 0; kk < 2; ++kk)
          acc[mf][nf + 2] = __builtin_amdgcn_mfma_f32_16x16x32_bf16(
              af[mf][kk], bf[nf][kk], acc[mf][nf + 2], 0, 0, 0);
    __builtin_amdgcn_s_setprio(0);
    if (t + 2 < NT)      asm volatile("s_waitcnt vmcnt(6)" ::: "memory");
    else if (t + 1 < NT) asm volatile("s_waitcnt vmcnt(0)" ::: "memory");
    if (t + 1 < NT) wgbar();
  }

#pragma unroll
  for (int nf = 0; nf < 4; ++nf) {
    int col = bn * 128 + wn * 64 + nf * 16 + qlane;
    float bv = bias[col];
#pragma unroll
    for (int mf = 0; mf < 4; ++mf) {
      int row0 = bm * 128 + wm * 64 + mf * 16 + kgrp * 4;
#pragma unroll
      for (int r = 0; r < 4; ++r)
        C[(size_t)(row0 + r) * N + col] = acc[mf][nf][r] + bv;
    }
  }
}

// ---------------- banded local attention (unchanged, proven) ----------------
__global__ __launch_bounds__(256, 2) void attn_local(
    const u16* __restrict__ qkv, const int* __restrict__ amask,
    u16* __restrict__ aout) {
  __shared__ __align__(16) u16 Kl[192][72];
  __shared__ __align__(16) u16 Vt[64][200];
  __shared__ __align__(16) u16 Pl[4][32][104];

  const int tid = threadIdx.x, wave = tid >> 6, lane = tid & 63;
  const int qlane = lane & 15, kgrp = lane >> 4;
  const int bz = blockIdx.x;
  const int qt = bz & 15, h = (bz >> 4) & 15, b = bz >> 8;
  const int qs0 = qt * 128;
  const int jt = qs0 - 32;
  const size_t rbase = (size_t)b * S_LEN;

  {
    const int r0 = tid >> 3, c0 = (tid & 7) * 8;
#pragma unroll
    for (int p = 0; p < 6; ++p) {
      int row = p * 32 + r0;
      int j = jt + row;
      u16 kv[8], vv[8];
      if (j >= 0 && j < S_LEN) {
        const u16* kp = qkv + (rbase + j) * QKV_LD + HID + h * 64 + c0;
        *(short8*)kv = *(const short8*)kp;
        *(short8*)vv = *(const short8*)(kp + HID);
      } else {
#pragma unroll
        for (int q = 0; q < 8; ++q) { kv[q] = 0; vv[q] = 0; }
      }
      *(short8*)&Kl[row][c0] = *(short8*)kv;
#pragma unroll
      for (int q = 0; q < 8; ++q) Vt[c0 + q][row] = vv[q];
    }
  }

  short8 qf[2][2];
#pragma unroll
  for (int mf = 0; mf < 2; ++mf)
#pragma unroll
    for (int kk = 0; kk < 2; ++kk)
      qf[mf][kk] = *(const short8*)(qkv +
          (rbase + qs0 + wave * 32 + mf * 16 + qlane) * QKV_LD +
          h * 64 + kk * 32 + kgrp * 8);

  __syncthreads();

  f32x4 sc[2][6] = {};
#pragma unroll
  for (int kk = 0; kk < 2; ++kk) {
    short8 kf[6];
#pragma unroll
    for (int nf = 0; nf < 6; ++nf)
      kf[nf] = *(const short8*)&Kl[wave * 32 + nf * 16 + qlane][kk * 32 + kgrp * 8];
#pragma unroll
    for (int mf = 0; mf < 2; ++mf)
#pragma unroll
      for (int nf = 0; nf < 6; ++nf)
        sc[mf][nf] = __builtin_amdgcn_mfma_f32_16x16x32_bf16(
            qf[mf][kk], kf[nf], sc[mf][nf], 0, 0, 0);
  }

  int jcol[6], mv[6];
#pragma unroll
  for (int nf = 0; nf < 6; ++nf) {
    int j = jt + wave * 32 + nf * 16 + qlane;
    jcol[nf] = j;
    mv[nf] = (j >= 0 && j < S_LEN) ? amask[rbase + j] : 0;
  }

  float inv[2][4];
#pragma unroll
  for (int mf = 0; mf < 2; ++mf) {
    const int irow0 = qs0 + wave * 32 + mf * 16 + kgrp * 4;
    float mx[4] = {-1e30f, -1e30f, -1e30f, -1e30f};
#pragma unroll
    for (int r = 0; r < 4; ++r) {
      int i = irow0 + r;
#pragma unroll
      for (int nf = 0; nf < 6; ++nf) {
        int d = i - jcol[nf];
        if (mv[nf] && d >= -32 && d <= 32) mx[r] = fmaxf(mx[r], sc[mf][nf][r]);
      }
    }
#pragma unroll
    for (int m = 1; m < 16; m <<= 1)
#pragma unroll
      for (int r = 0; r < 4; ++r)
        mx[r] = fmaxf(mx[r], __shfl_xor(mx[r], m));
    float sm[4] = {0.f, 0.f, 0.f, 0.f};
#pragma unroll
    for (int r = 0; r < 4; ++r) {
      int i = irow0 + r;
#pragma unroll
      for (int nf = 0; nf < 6; ++nf) {
        int d = i - jcol[nf];
        bool val = mv[nf] && d >= -32 && d <= 32;
        float p = val ? __expf((sc[mf][nf][r] - mx[r]) * 0.125f) : 0.f;
        sc[mf][nf][r] = p;
        sm[r] += p;
      }
    }
#pragma unroll
    for (int m = 1; m < 16; m <<= 1)
#pragma unroll
      for (int r = 0; r < 4; ++r)
        sm[r] += __shfl_xor(sm[r], m);
#pragma unroll
    for (int r = 0; r < 4; ++r)
      inv[mf][r] = sm[r] > 0.f ? 1.f / sm[r] : 0.f;
#pragma unroll
    for (int nf = 0; nf < 6; ++nf)
#pragma unroll
      for (int r = 0; r < 4; ++r)
        Pl[wave][mf * 16 + kgrp * 4 + r][nf * 16 + qlane] = f2bf(sc[mf][nf][r]);
  }
  __syncthreads();

  f32x4 oc[2][4] = {};
#pragma unroll
  for (int ks = 0; ks < 3; ++ks) {
    short8 pa[2], vb[4];
#pragma unroll
    for (int mf = 0; mf < 2; ++mf)
      pa[mf] = *(const short8*)&Pl[wave][mf * 16 + qlane][ks * 32 + kgrp * 8];
#pragma unroll
    for (int nf = 0; nf < 4; ++nf)
      vb[nf] = *(const short8*)&Vt[nf * 16 + qlane][wave * 32 + ks * 32 + kgrp * 8];
#pragma unroll
    for (int mf = 0; mf < 2; ++mf)
#pragma unroll
      for (int nf = 0; nf < 4; ++nf)
        oc[mf][nf] = __builtin_amdgcn_mfma_f32_16x16x32_bf16(
            pa[mf], vb[nf], oc[mf][nf], 0, 0, 0);
  }

#pragma unroll
  for (int mf = 0; mf < 2; ++mf)
#pragma unroll
    for (int nf = 0; nf < 4; ++nf)
#pragma unroll
      for (int r = 0; r < 4; ++r) {
        size_t row = rbase + qs0 + wave * 32 + mf * 16 + kgrp * 4 + r;
        aout[row * HID + h * 64 + nf * 16 + qlane] =
            f2bf(oc[mf][nf][r] * inv[mf][r]);
      }
}

// ---------------- launch ----------------
extern "C" void kernel_launch(void* const* d_in, const int* in_sizes, int n_in,
                              void* d_out, int out_size, void* d_ws, size_t ws_size,
                              hipStream_t stream) {
  const float* x  = (const float*)d_in[0];
  const int* amask = (const int*)d_in[1];
  const float* Wq = (const float*)d_in[2];
  const float* bq = (const float*)d_in[3];
  const float* Wk = (const float*)d_in[4];
  const float* bk = (const float*)d_in[5];
  const float* Wv = (const float*)d_in[6];
  const float* bv = (const float*)d_in[7];
  const float* Wo = (const float*)d_in[8];
  const float* bo = (const float*)d_in[9];
  float* out = (float*)d_out;

  char* w = (char*)d_ws;
  u16* xb    = (u16*)w;   w += (size_t)M_ROWS * HID * 2;
  u16* wqkvt = (u16*)w;   w += (size_t)3072 * 1024 * 2;
  u16* wot   = (u16*)w;   w += (size_t)1024 * 1024 * 2;
  float* bqkv = (float*)w; w += 3072 * 4 + 256;
  u16* qkv   = (u16*)w;   w += (size_t)M_ROWS * 3072 * 2;
  u16* aout  = (u16*)w;   w += (size_t)M_ROWS * HID * 2;

  prep<<<8193, 256, 0, stream>>>(x, xb, bq, bk, bv, bqkv,
                                 Wq, Wk, Wv, Wo, wqkvt, wot);
  gemm_k1<<<1024, 256, 0, stream>>>(xb, wqkvt, bqkv, qkv);
  attn_local<<<1024, 256, 0, stream>>>(qkv, amask, aout);
  gemm_k2<<<512, 256, 0, stream>>>(aout, wot, bo, out);
}

// Round 9
// 112.544 us; speedup vs baseline: 1.1388x; 1.0659x over previous
//
#include <hip/hip_runtime.h>
#include <stdint.h>

typedef unsigned short u16;
typedef __attribute__((ext_vector_type(8))) short short8;
typedef __attribute__((ext_vector_type(4))) float f32x4;

#define S_LEN 2048
#define HID   1024
#define QKV_LD 3072
#define M_ROWS 8192   // B*S

__device__ __forceinline__ u16 f2bf(float f) {
  unsigned u = __float_as_uint(f);
  unsigned r = (u + 0x7fffu + ((u >> 16) & 1u)) >> 16;
  return (u16)r;
}

__device__ __forceinline__ void gload16(const u16* g, u16* l) {
  __builtin_amdgcn_global_load_lds(
      (const __attribute__((address_space(1))) unsigned int*)(g),
      (__attribute__((address_space(3))) unsigned int*)(l),
      16, 0, 0);
}

__device__ __forceinline__ void wgbar() {
  asm volatile("" ::: "memory");
  __builtin_amdgcn_s_barrier();
  asm volatile("" ::: "memory");
}

// -------- fused prep: cvt x->bf16, pack biases, transpose 4 weights --------
__global__ __launch_bounds__(256) void prep(
    const float* __restrict__ x, u16* __restrict__ xb,
    const float* __restrict__ bq, const float* __restrict__ bk,
    const float* __restrict__ bv, float* __restrict__ bqkv,
    const float* __restrict__ Wq, const float* __restrict__ Wk,
    const float* __restrict__ Wv, const float* __restrict__ Wo,
    u16* __restrict__ wqkvt, u16* __restrict__ wot) {
  __shared__ float tile[32][33];
  const int bid = blockIdx.x;
  if (bid < 4096) {                      // x: f32 -> bf16, 8 elem/thread
    int i = (bid * 256 + threadIdx.x) * 8;
    float4 a = *(const float4*)(x + i);
    float4 b = *(const float4*)(x + i + 4);
    u16 t[8];
    t[0] = f2bf(a.x); t[1] = f2bf(a.y); t[2] = f2bf(a.z); t[3] = f2bf(a.w);
    t[4] = f2bf(b.x); t[5] = f2bf(b.y); t[6] = f2bf(b.z); t[7] = f2bf(b.w);
    *(short8*)(xb + i) = *(short8*)t;
    return;
  }
  if (bid == 4096) {                     // bias pack
    for (int i = threadIdx.x; i < 3072; i += 256)
      bqkv[i] = (i < 1024) ? bq[i] : (i < 2048) ? bk[i - 1024] : bv[i - 2048];
    return;
  }
  const int wid = bid - 4097;            // weight transpose: f32[K][N]->bf16[N][K]
  const int z = wid >> 10, rem = wid & 1023;
  const float* in = (z == 0) ? Wq : (z == 1) ? Wk : (z == 2) ? Wv : Wo;
  u16* out = (z < 3) ? (wqkvt + (size_t)z * 1024 * 1024) : wot;
  int tx = threadIdx.x & 31, ty = threadIdx.x >> 5;
  int n0 = (rem & 31) * 32, k0 = (rem >> 5) * 32;
#pragma unroll
  for (int i = 0; i < 32; i += 8)
    tile[ty + i][tx] = in[(size_t)(k0 + ty + i) * 1024 + n0 + tx];
  __syncthreads();
#pragma unroll
  for (int i = 0; i < 32; i += 8)
    out[(size_t)(n0 + ty + i) * 1024 + k0 + tx] = f2bf(tile[tx][ty + i]);
}

// ---------------- GEMM1: 2-phase ring-2, 8 waves (16 waves/CU) ----------
// C[8192,3072] = A * Bt^T + bias (bf16 out).  BM=128 x BN=192, BK=64,
// 8 waves (2M x 4N), per-wave 64x48 (4x3 frags, acc 48 VGPR).  Same LDS
// budget as round 6: ring-2 x 40 KiB = 80 KiB -> 2 blocks/CU = 16
// waves/CU (4/SIMD) for latency hiding (r6's 8 waves/CU was gap-bound:
// 4088 cyc/tile-pair vs 466 MFMA + 940 LDS-port).
// Staging units are 64 rows x 64 cols (512 thr x 16 B).  Read map:
//   P1 reads A (all) + B nf0,1 (rows wn*48..+31 -> parts of ALL B units)
//   P2 reads B nf2   (rows wn*48+32..47 -> also touches B units 0,1,2)
// => B units can only be re-staged CROSS-buffer in P1 (B(t+1), 3 loads;
//    other buffer holds t-1, fully read before end-of-(t-1) barrier);
//    A staged same-buffer in P2 (A(t+2), 2 loads; A last read P1 + bar).
// Gate at tile end: only A(t+2)'s 2 loads are newer than tile t+1's last
// piece (B(t+1), issued P1(t)) -> vmcnt(2) proves t+1 landed.
// XOR slot swizzle slot^=(row&7); all frag row-groups are 16 consecutive
// rows with key = qlane&7 -> the proven 0-conflict pattern (r1-r7).
__global__ __launch_bounds__(512, 2) void gemm_k1(
    const u16* __restrict__ A, const u16* __restrict__ Bt,
    const float* __restrict__ bias, u16* __restrict__ C) {
  constexpr int K = 1024, NT = 16, N = 3072;
  constexpr int AU = 128 * 64;            // 8192 u16
  constexpr int SLAB = 320 * 64;          // 20480 u16 (40 KiB)
  __shared__ __align__(16) u16 smem[2 * SLAB];

  const int tid = threadIdx.x;
  const int wave = tid >> 6, lane = tid & 63;
  const int qlane = lane & 15, kgrp = lane >> 4;
  const int wm = wave >> 2, wn = wave & 3;     // 2M x 4N
  int wg = blockIdx.x;
  wg = (wg & 7) * 128 + (wg >> 3);        // 1024 blocks, bijective XCD swizzle
  const int bm = wg >> 4, bn = wg & 15;   // 64 x 16

  // staging: unit = 64 rows x 64 cols = 8 KiB = 512 thr x 16 B
  const int srow = tid >> 3;              // 0..63
  const int sslot = (tid & 7) ^ (srow & 7);
  uint32_t gA[2], gB[3];
#pragma unroll
  for (int u = 0; u < 2; ++u)
    gA[u] = (uint32_t)((bm * 128 + u * 64 + srow) * K + sslot * 8);
#pragma unroll
  for (int u = 0; u < 3; ++u)
    gB[u] = (uint32_t)((bn * 192 + u * 64 + srow) * K + sslot * 8);

  auto stgA = [&](int t, int u) {
    gload16(A + (size_t)gA[u] + t * 64, &smem[(t & 1) * SLAB + u * 4096 + tid * 8]);
  };
  auto stgB = [&](int t, int u) {
    gload16(Bt + (size_t)gB[u] + t * 64, &smem[(t & 1) * SLAB + AU + u * 4096 + tid * 8]);
  };

  // frag base addresses (u16 units); row&7 == qlane&7 for every frag
  const int key7 = qlane & 7;
  int aaddr[4], baddr[3];
#pragma unroll
  for (int mf = 0; mf < 4; ++mf)
    aaddr[mf] = (wm * 64 + mf * 16 + qlane) * 64;
#pragma unroll
  for (int nf = 0; nf < 3; ++nf)
    baddr[nf] = AU + (wn * 48 + nf * 16 + qlane) * 64;

  f32x4 acc[4][3] = {};
  short8 af[4][2], bf[2][2];

  // prologue: tile0 (5 loads) + A(1) (2 loads)
  stgA(0, 0); stgA(0, 1);
  stgB(0, 0); stgB(0, 1); stgB(0, 2);
  stgA(1, 0); stgA(1, 1);
  asm volatile("s_waitcnt vmcnt(2)" ::: "memory");   // tile 0 landed
  wgbar();

  for (int t = 0; t < NT; ++t) {
    const u16* bp = &smem[(t & 1) * SLAB];

    // ---- P1: read A (8) + B nf0,1 (4); stage B(t+1) x3 (other buffer) ----
#pragma unroll
    for (int mf = 0; mf < 4; ++mf)
#pragma unroll
      for (int kk = 0; kk < 2; ++kk)
        af[mf][kk] = *(const short8*)&bp[aaddr[mf] + (((kk * 4 + kgrp) ^ key7) * 8)];
#pragma unroll
    for (int nf = 0; nf < 2; ++nf)
#pragma unroll
      for (int kk = 0; kk < 2; ++kk)
        bf[nf][kk] = *(const short8*)&bp[baddr[nf] + (((kk * 4 + kgrp) ^ key7) * 8)];
    if (t + 1 < NT) { stgB(t + 1, 0); stgB(t + 1, 1); stgB(t + 1, 2); }
    wgbar();
    asm volatile("s_waitcnt lgkmcnt(0)" ::: "memory");
    __builtin_amdgcn_s_setprio(1);
#pragma unroll
    for (int mf = 0; mf < 4; ++mf)
#pragma unroll
      for (int nf = 0; nf < 2; ++nf)
#pragma unroll
        for (int kk = 0; kk < 2; ++kk)
          acc[mf][nf] = __builtin_amdgcn_mfma_f32_16x16x32_bf16(
              af[mf][kk], bf[nf][kk], acc[mf][nf], 0, 0, 0);
    __builtin_amdgcn_s_setprio(0);
    wgbar();

    // ---- P2: read B nf2 (2); stage A(t+2) x2 (current buffer) ----
#pragma unroll
    for (int kk = 0; kk < 2; ++kk)
      bf[0][kk] = *(const short8*)&bp[baddr[2] + (((kk * 4 + kgrp) ^ key7) * 8)];
    if (t + 2 < NT) { stgA(t + 2, 0); stgA(t + 2, 1); }
    wgbar();
    asm volatile("s_waitcnt lgkmcnt(0)" ::: "memory");
    __builtin_amdgcn_s_setprio(1);
#pragma unroll
    for (int mf = 0; mf < 4; ++mf)
#pragma unroll
      for (int kk = 0; kk < 2; ++kk)
        acc[mf][2] = __builtin_amdgcn_mfma_f32_16x16x32_bf16(
            af[mf][kk], bf[0][kk], acc[mf][2], 0, 0, 0);
    __builtin_amdgcn_s_setprio(0);
    if (t + 2 < NT)      asm volatile("s_waitcnt vmcnt(2)" ::: "memory");
    else if (t + 1 < NT) asm volatile("s_waitcnt vmcnt(0)" ::: "memory");
    if (t + 1 < NT) wgbar();
  }

  // epilogue
#pragma unroll
  for (int nf = 0; nf < 3; ++nf) {
    int col = bn * 192 + wn * 48 + nf * 16 + qlane;
    float bv = bias[col];
#pragma unroll
    for (int mf = 0; mf < 4; ++mf) {
      int row0 = bm * 128 + wm * 64 + mf * 16 + kgrp * 4;
#pragma unroll
      for (int r = 0; r < 4; ++r)
        C[(size_t)(row0 + r) * N + col] = f2bf(acc[mf][nf][r] + bv);
    }
  }
}

// ---------------- GEMM2: 2-phase ring-2 counted-vmcnt (round-6, proven) ---
__global__ __launch_bounds__(256, 2) void gemm_k2(
    const u16* __restrict__ A, const u16* __restrict__ Bt,
    const float* __restrict__ bias, float* __restrict__ C) {
  constexpr int K = 1024, NT = 16, N = 1024;
  constexpr int AU = 128 * 64;            // 8192 u16
  constexpr int SLAB = 256 * 64;          // 16384 u16 (32 KiB)
  __shared__ __align__(16) u16 smem[2 * SLAB];

  const int tid = threadIdx.x;
  const int wave = tid >> 6, lane = tid & 63;
  const int qlane = lane & 15, kgrp = lane >> 4;
  const int wm = wave >> 1, wn = wave & 1;
  int wg = blockIdx.x;
  wg = (wg & 7) * 64 + (wg >> 3);         // 512 blocks, bijective
  const int bm = wg >> 3, bn = wg & 7;    // 64 x 8

  const int srow = tid >> 3;
  const int sslot = (tid & 7) ^ (srow & 7);
  uint32_t gA[4], gB[4];
#pragma unroll
  for (int u = 0; u < 4; ++u) {
    gA[u] = (uint32_t)((bm * 128 + u * 32 + srow) * K + sslot * 8);
    gB[u] = (uint32_t)((bn * 128 + u * 32 + srow) * K + sslot * 8);
  }
  auto stgA = [&](int t, int u) {
    gload16(A + (size_t)gA[u] + t * 64, &smem[(t & 1) * SLAB + u * 2048 + tid * 8]);
  };
  auto stgB = [&](int t, int u) {
    gload16(Bt + (size_t)gB[u] + t * 64, &smem[(t & 1) * SLAB + AU + u * 2048 + tid * 8]);
  };

  int aaddr[4], baddr[4];
#pragma unroll
  for (int f = 0; f < 4; ++f) {
    aaddr[f] = (wm * 64 + f * 16 + qlane) * 64;
    baddr[f] = AU + (wn * 64 + f * 16 + qlane) * 64;
  }
  const int arow7 = (wm * 64 + qlane) & 7;
  const int brow7 = (wn * 64 + qlane) & 7;

  f32x4 acc[4][4] = {};
  short8 af[4][2], bf[2][2];

#pragma unroll
  for (int u = 0; u < 4; ++u) stgA(0, u);
#pragma unroll
  for (int u = 0; u < 4; ++u) stgB(0, u);
#pragma unroll
  for (int u = 0; u < 4; ++u) stgA(1, u);
  stgB(1, 0); stgB(1, 2);
  asm volatile("s_waitcnt vmcnt(6)" ::: "memory");
  wgbar();

  for (int t = 0; t < NT; ++t) {
    const u16* bp = &smem[(t & 1) * SLAB];

    // ---- P1 ----
#pragma unroll
    for (int mf = 0; mf < 4; ++mf)
#pragma unroll
      for (int kk = 0; kk < 2; ++kk)
        af[mf][kk] = *(const short8*)&bp[aaddr[mf] + (((kk * 4 + kgrp) ^ arow7) * 8)];
#pragma unroll
    for (int nf = 0; nf < 2; ++nf)
#pragma unroll
      for (int kk = 0; kk < 2; ++kk)
        bf[nf][kk] = *(const short8*)&bp[baddr[nf] + (((kk * 4 + kgrp) ^ brow7) * 8)];
    if (t + 1 < NT) { stgB(t + 1, 1); stgB(t + 1, 3); }
    wgbar();
    asm volatile("s_waitcnt lgkmcnt(0)" ::: "memory");
    __builtin_amdgcn_s_setprio(1);
#pragma unroll
    for (int mf = 0; mf < 4; ++mf)
#pragma unroll
      for (int nf = 0; nf < 2; ++nf)
#pragma unroll
        for (int kk = 0; kk < 2; ++kk)
          acc[mf][nf] = __builtin_amdgcn_mfma_f32_16x16x32_bf16(
              af[mf][kk], bf[nf][kk], acc[mf][nf], 0, 0, 0);
    __builtin_amdgcn_s_setprio(0);
    wgbar();

    // ---- P2 ----
#pragma unroll
    for (int nf = 0; nf < 2; ++nf)
#pragma unroll
      for (int kk = 0; kk < 2; ++kk)
        bf[nf][kk] = *(const short8*)&bp[baddr[nf + 2] + (((kk * 4 + kgrp) ^ brow7) * 8)];
    if (t + 2 < NT) {
      stgA(t + 2, 0); stgA(t + 2, 1); stgA(t + 2, 2); stgA(t + 2, 3);
      stgB(t + 2, 0); stgB(t + 2, 2);
    }
    wgbar();
    asm volatile("s_waitcnt lgkmcnt(0)" ::: "memory");
    __builtin_amdgcn_s_setprio(1);
#pragma unroll
    for (int mf = 0; mf < 4; ++mf)
#pragma unroll
      for (int nf = 0; nf < 2; ++nf)
#pragma unroll
        for (int kk = 0; kk < 2; ++kk)
          acc[mf][nf + 2] = __builtin_amdgcn_mfma_f32_16x16x32_bf16(
              af[mf][kk], bf[nf][kk], acc[mf][nf + 2], 0, 0, 0);
    __builtin_amdgcn_s_setprio(0);
    if (t + 2 < NT)      asm volatile("s_waitcnt vmcnt(6)" ::: "memory");
    else if (t + 1 < NT) asm volatile("s_waitcnt vmcnt(0)" ::: "memory");
    if (t + 1 < NT) wgbar();
  }

#pragma unroll
  for (int nf = 0; nf < 4; ++nf) {
    int col = bn * 128 + wn * 64 + nf * 16 + qlane;
    float bv = bias[col];
#pragma unroll
    for (int mf = 0; mf < 4; ++mf) {
      int row0 = bm * 128 + wm * 64 + mf * 16 + kgrp * 4;
#pragma unroll
      for (int r = 0; r < 4; ++r)
        C[(size_t)(row0 + r) * N + col] = acc[mf][nf][r] + bv;
    }
  }
}

// ---------------- banded local attention (+ XCD-clustered blockIdx) -------
__global__ __launch_bounds__(256, 2) void attn_local(
    const u16* __restrict__ qkv, const int* __restrict__ amask,
    u16* __restrict__ aout) {
  __shared__ __align__(16) u16 Kl[192][72];
  __shared__ __align__(16) u16 Vt[64][200];
  __shared__ __align__(16) u16 Pl[4][32][104];

  const int tid = threadIdx.x, wave = tid >> 6, lane = tid & 63;
  const int qlane = lane & 15, kgrp = lane >> 4;
  // bijective XCD swizzle: each XCD gets contiguous logical range =
  // one batch x 8 heads x all 16 q-tiles -> overlapping K/V windows L2-hit
  const int rbz = blockIdx.x;
  const int bz = (rbz & 7) * 128 + (rbz >> 3);
  const int qt = bz & 15, h = (bz >> 4) & 15, b = bz >> 8;
  const int qs0 = qt * 128;
  const int jt = qs0 - 32;
  const size_t rbase = (size_t)b * S_LEN;

  {
    const int r0 = tid >> 3, c0 = (tid & 7) * 8;
#pragma unroll
    for (int p = 0; p < 6; ++p) {
      int row = p * 32 + r0;
      int j = jt + row;
      u16 kv[8], vv[8];
      if (j >= 0 && j < S_LEN) {
        const u16* kp = qkv + (rbase + j) * QKV_LD + HID + h * 64 + c0;
        *(short8*)kv = *(const short8*)kp;
        *(short8*)vv = *(const short8*)(kp + HID);
      } else {
#pragma unroll
        for (int q = 0; q < 8; ++q) { kv[q] = 0; vv[q] = 0; }
      }
      *(short8*)&Kl[row][c0] = *(short8*)kv;
#pragma unroll
      for (int q = 0; q < 8; ++q) Vt[c0 + q][row] = vv[q];
    }
  }

  short8 qf[2][2];
#pragma unroll
  for (int mf = 0; mf < 2; ++mf)
#pragma unroll
    for (int kk = 0; kk < 2; ++kk)
      qf[mf][kk] = *(const short8*)(qkv +
          (rbase + qs0 + wave * 32 + mf * 16 + qlane) * QKV_LD +
          h * 64 + kk * 32 + kgrp * 8);

  __syncthreads();

  f32x4 sc[2][6] = {};
#pragma unroll
  for (int kk = 0; kk < 2; ++kk) {
    short8 kf[6];
#pragma unroll
    for (int nf = 0; nf < 6; ++nf)
      kf[nf] = *(const short8*)&Kl[wave * 32 + nf * 16 + qlane][kk * 32 + kgrp * 8];
#pragma unroll
    for (int mf = 0; mf < 2; ++mf)
#pragma unroll
      for (int nf = 0; nf < 6; ++nf)
        sc[mf][nf] = __builtin_amdgcn_mfma_f32_16x16x32_bf16(
            qf[mf][kk], kf[nf], sc[mf][nf], 0, 0, 0);
  }

  int jcol[6], mv[6];
#pragma unroll
  for (int nf = 0; nf < 6; ++nf) {
    int j = jt + wave * 32 + nf * 16 + qlane;
    jcol[nf] = j;
    mv[nf] = (j >= 0 && j < S_LEN) ? amask[rbase + j] : 0;
  }

  float inv[2][4];
#pragma unroll
  for (int mf = 0; mf < 2; ++mf) {
    const int irow0 = qs0 + wave * 32 + mf * 16 + kgrp * 4;
    float mx[4] = {-1e30f, -1e30f, -1e30f, -1e30f};
#pragma unroll
    for (int r = 0; r < 4; ++r) {
      int i = irow0 + r;
#pragma unroll
      for (int nf = 0; nf < 6; ++nf) {
        int d = i - jcol[nf];
        if (mv[nf] && d >= -32 && d <= 32) mx[r] = fmaxf(mx[r], sc[mf][nf][r]);
      }
    }
#pragma unroll
    for (int m = 1; m < 16; m <<= 1)
#pragma unroll
      for (int r = 0; r < 4; ++r)
        mx[r] = fmaxf(mx[r], __shfl_xor(mx[r], m));
    float sm[4] = {0.f, 0.f, 0.f, 0.f};
#pragma unroll
    for (int r = 0; r < 4; ++r) {
      int i = irow0 + r;
#pragma unroll
      for (int nf = 0; nf < 6; ++nf) {
        int d = i - jcol[nf];
        bool val = mv[nf] && d >= -32 && d <= 32;
        float p = val ? __expf((sc[mf][nf][r] - mx[r]) * 0.125f) : 0.f;
        sc[mf][nf][r] = p;
        sm[r] += p;
      }
    }
#pragma unroll
    for (int m = 1; m < 16; m <<= 1)
#pragma unroll
      for (int r = 0; r < 4; ++r)
        sm[r] += __shfl_xor(sm[r], m);
#pragma unroll
    for (int r = 0; r < 4; ++r)
      inv[mf][r] = sm[r] > 0.f ? 1.f / sm[r] : 0.f;
#pragma unroll
    for (int nf = 0; nf < 6; ++nf)
#pragma unroll
      for (int r = 0; r < 4; ++r)
        Pl[wave][mf * 16 + kgrp * 4 + r][nf * 16 + qlane] = f2bf(sc[mf][nf][r]);
  }
  __syncthreads();

  f32x4 oc[2][4] = {};
#pragma unroll
  for (int ks = 0; ks < 3; ++ks) {
    short8 pa[2], vb[4];
#pragma unroll
    for (int mf = 0; mf < 2; ++mf)
      pa[mf] = *(const short8*)&Pl[wave][mf * 16 + qlane][ks * 32 + kgrp * 8];
#pragma unroll
    for (int nf = 0; nf < 4; ++nf)
      vb[nf] = *(const short8*)&Vt[nf * 16 + qlane][wave * 32 + ks * 32 + kgrp * 8];
#pragma unroll
    for (int mf = 0; mf < 2; ++mf)
#pragma unroll
      for (int nf = 0; nf < 4; ++nf)
        oc[mf][nf] = __builtin_amdgcn_mfma_f32_16x16x32_bf16(
            pa[mf], vb[nf], oc[mf][nf], 0, 0, 0);
  }

#pragma unroll
  for (int mf = 0; mf < 2; ++mf)
#pragma unroll
    for (int nf = 0; nf < 4; ++nf)
#pragma unroll
      for (int r = 0; r < 4; ++r) {
        size_t row = rbase + qs0 + wave * 32 + mf * 16 + kgrp * 4 + r;
        aout[row * HID + h * 64 + nf * 16 + qlane] =
            f2bf(oc[mf][nf][r] * inv[mf][r]);
      }
}

// ---------------- launch ----------------
extern "C" void kernel_launch(void* const* d_in, const int* in_sizes, int n_in,
                              void* d_out, int out_size, void* d_ws, size_t ws_size,
                              hipStream_t stream) {
  const float* x  = (const float*)d_in[0];
  const int* amask = (const int*)d_in[1];
  const float* Wq = (const float*)d_in[2];
  const float* bq = (const float*)d_in[3];
  const float* Wk = (const float*)d_in[4];
  const float* bk = (const float*)d_in[5];
  const float* Wv = (const float*)d_in[6];
  const float* bv = (const float*)d_in[7];
  const float* Wo = (const float*)d_in[8];
  const float* bo = (const float*)d_in[9];
  float* out = (float*)d_out;

  char* w = (char*)d_ws;
  u16* xb    = (u16*)w;   w += (size_t)M_ROWS * HID * 2;
  u16* wqkvt = (u16*)w;   w += (size_t)3072 * 1024 * 2;
  u16* wot   = (u16*)w;   w += (size_t)1024 * 1024 * 2;
  float* bqkv = (float*)w; w += 3072 * 4 + 256;
  u16* qkv   = (u16*)w;   w += (size_t)M_ROWS * 3072 * 2;
  u16* aout  = (u16*)w;   w += (size_t)M_ROWS * HID * 2;

  prep<<<8193, 256, 0, stream>>>(x, xb, bq, bk, bv, bqkv,
                                 Wq, Wk, Wv, Wo, wqkvt, wot);
  gemm_k1<<<1024, 512, 0, stream>>>(xb, wqkvt, bqkv, qkv);
  attn_local<<<1024, 256, 0, stream>>>(qkv, amask, aout);
  gemm_k2<<<512, 256, 0, stream>>>(aout, wot, bo, out);
}